// Round 1
// baseline (328.926 us; speedup 1.0000x reference)
//
#include <hip/hip_runtime.h>

#define TOK    18464      // 32*577 tokens
#define SEQ    577
#define EMB    768
#define NH     12
#define HD     64
#define BHn    384        // 32*12
#define QKVN   2304       // 3*768
#define HEADSZ 36928      // SEQ*HD
#define PLANE  14180352   // TOK*EMB = B*H*S*D

typedef float f32x4 __attribute__((ext_vector_type(4)));
typedef short s16x8 __attribute__((ext_vector_type(8)));

__device__ __forceinline__ unsigned short f2bf(float f) {
  unsigned u = __builtin_bit_cast(unsigned, f);
  return (unsigned short)((u + 0x7fffu + ((u >> 16) & 1u)) >> 16);
}

__device__ __forceinline__ void gload16(const void* g, void* l) {
  __builtin_amdgcn_global_load_lds(
      (const __attribute__((address_space(1))) void*)g,
      (__attribute__((address_space(3))) void*)l, 16, 0, 0);
}

// ---------------- fp32 -> bf16 conversion (x) ----------------
__global__ void cvt_x(const float* __restrict__ src, short* __restrict__ dst, int n8) {
  int i = blockIdx.x * blockDim.x + threadIdx.x;
  if (i >= n8) return;
  const float4* s4 = reinterpret_cast<const float4*>(src + (size_t)i * 8);
  float4 a = s4[0], b = s4[1];
  s16x8 o;
  o[0] = (short)f2bf(a.x); o[1] = (short)f2bf(a.y);
  o[2] = (short)f2bf(a.z); o[3] = (short)f2bf(a.w);
  o[4] = (short)f2bf(b.x); o[5] = (short)f2bf(b.y);
  o[6] = (short)f2bf(b.z); o[7] = (short)f2bf(b.w);
  *reinterpret_cast<s16x8*>(dst + (size_t)i * 8) = o;
}

// ---------------- weight conversion: wq|wk|wv -> wqkv, w_proj -> wpb ----------------
__global__ void cvt_w(const float* __restrict__ wq, const float* __restrict__ wk,
                      const float* __restrict__ wv, const float* __restrict__ wp,
                      short* __restrict__ wqkv, short* __restrict__ wpb) {
  int tid = blockIdx.x * blockDim.x + threadIdx.x;   // 294912 threads
  if (tid >= 294912) return;
  int region = tid / 73728;                          // 589824/8
  int off = (tid % 73728) * 8;
  const float* s; short* d;
  if (region == 0)      { s = wq + off; d = wqkv + off; }
  else if (region == 1) { s = wk + off; d = wqkv + 589824 + off; }
  else if (region == 2) { s = wv + off; d = wqkv + 2 * 589824 + off; }
  else                  { s = wp + off; d = wpb + off; }
  const float4* s4 = reinterpret_cast<const float4*>(s);
  float4 a = s4[0], b = s4[1];
  s16x8 o;
  o[0] = (short)f2bf(a.x); o[1] = (short)f2bf(a.y);
  o[2] = (short)f2bf(a.z); o[3] = (short)f2bf(a.w);
  o[4] = (short)f2bf(b.x); o[5] = (short)f2bf(b.y);
  o[6] = (short)f2bf(b.z); o[7] = (short)f2bf(b.w);
  *reinterpret_cast<s16x8*>(d) = o;
}

// ---------------- 128x128 bf16 GEMM, B^T layout (m97 structure) ----------------
// MODE 0: C[row,col] scattered to QKV bf16 [3][B][H][S][D]
// MODE 1: C[row,col] = acc + bias[col] -> fp32 out
template <int MODE>
__launch_bounds__(256)
__global__ void gemm_bt(const short* __restrict__ A, const short* __restrict__ Bw,
                        short* __restrict__ qkv_out, float* __restrict__ out,
                        const float* __restrict__ bias, int M, int nnt) {
  __shared__ short As[128 * 32];
  __shared__ short Bs[128 * 32];
  int tn = blockIdx.x % nnt;
  int tm = blockIdx.x / nnt;
  int tid = threadIdx.x;
  int w = tid >> 6, lane = tid & 63;
  int wm = w >> 1, wn = w & 1;
  int lr = lane & 15, lg = lane >> 4;
  int m0 = tm * 128, n0 = tn * 128;

  f32x4 acc[4][4] = {};

  int srow = tid >> 2;             // 0..63
  int scol = (tid & 3) * 8;        // 0,8,16,24

  for (int kt = 0; kt < 24; ++kt) {
    int kb = kt * 32;
    __syncthreads();
    #pragma unroll
    for (int it = 0; it < 2; ++it) {
      int row = srow + it * 64;
      int gr = m0 + row; if (gr >= M) gr = M - 1;
      gload16(A + (size_t)gr * EMB + kb + scol, (char*)As + w * 1024 + it * 4096);
      int rb = n0 + row;           // N is a multiple of 128 for both GEMMs
      gload16(Bw + (size_t)rb * EMB + kb + scol, (char*)Bs + w * 1024 + it * 4096);
    }
    __syncthreads();
    s16x8 af[4], bfr[4];
    #pragma unroll
    for (int f = 0; f < 4; ++f) {
      af[f]  = *reinterpret_cast<const s16x8*>(&As[(wm * 64 + f * 16 + lr) * 32 + lg * 8]);
      bfr[f] = *reinterpret_cast<const s16x8*>(&Bs[(wn * 64 + f * 16 + lr) * 32 + lg * 8]);
    }
    #pragma unroll
    for (int i = 0; i < 4; ++i)
      #pragma unroll
      for (int j = 0; j < 4; ++j)
        acc[i][j] = __builtin_amdgcn_mfma_f32_16x16x32_bf16(af[i], bfr[j], acc[i][j], 0, 0, 0);
  }

  int mbase = m0 + wm * 64;
  int nbase = n0 + wn * 64;
  #pragma unroll
  for (int i = 0; i < 4; ++i) {
    #pragma unroll
    for (int j = 0; j < 4; ++j) {
      #pragma unroll
      for (int r = 0; r < 4; ++r) {
        int row = mbase + i * 16 + lg * 4 + r;
        int col = nbase + j * 16 + lr;
        if (row < M) {
          float v = acc[i][j][r];
          if (MODE == 0) {
            int which = (col >= 1536) ? 2 : ((col >= 768) ? 1 : 0);
            int rem = col - which * 768;
            int h = rem >> 6, d = rem & 63;
            int b = row / SEQ;
            int s = row - b * SEQ;
            qkv_out[(size_t)which * PLANE + ((size_t)b * NH + h) * HEADSZ + s * HD + d] =
                (short)f2bf(v);
          } else {
            out[(size_t)row * EMB + col] = v + bias[col];
          }
        }
      }
    }
  }
}

// ---------------- flash attention: one block per (b,h,q-tile of 64) ----------------
__launch_bounds__(256)
__global__ void attn(const short* __restrict__ qkv, short* __restrict__ cat) {
  int bh = blockIdx.x / 10;
  int qt = blockIdx.x % 10;
  int b = bh / NH, h = bh % NH;
  const short* Q  = qkv + (size_t)bh * HEADSZ;
  const short* Kp = qkv + (size_t)PLANE + (size_t)bh * HEADSZ;
  const short* Vp = qkv + 2 * (size_t)PLANE + (size_t)bh * HEADSZ;

  __shared__ short Ks[64 * 72];
  __shared__ short Vt[64 * 72];
  __shared__ short Pl[4][16 * 72];

  int tid = threadIdx.x, w = tid >> 6, lane = tid & 63;
  int lr = lane & 15, lg = lane >> 4;
  int q0 = qt * 64;

  // Q fragments in registers for the whole kernel
  s16x8 qf[2];
  {
    int row = q0 + w * 16 + lr; if (row >= SEQ) row = SEQ - 1;
    #pragma unroll
    for (int kk = 0; kk < 2; ++kk)
      qf[kk] = *reinterpret_cast<const s16x8*>(&Q[row * HD + kk * 32 + lg * 8]);
  }

  f32x4 acco[4] = {};
  float mrow[4], lsum[4];
  #pragma unroll
  for (int r = 0; r < 4; ++r) { mrow[r] = -1e30f; lsum[r] = 0.f; }

  int rowk = tid >> 2;            // 0..63
  int colk = (tid & 3) * 16;      // 0,16,32,48

  for (int tt = 0; tt < 10; ++tt) {
    int t0 = tt * 64;
    __syncthreads();
    // stage K (row-major, padded stride 72) and V transposed (Vt[d][t], stride 72)
    {
      int gr = t0 + rowk; if (gr >= SEQ) gr = SEQ - 1;
      #pragma unroll
      for (int p = 0; p < 2; ++p) {
        s16x8 kv = *reinterpret_cast<const s16x8*>(&Kp[gr * HD + colk + p * 8]);
        *reinterpret_cast<s16x8*>(&Ks[rowk * 72 + colk + p * 8]) = kv;
        s16x8 vv = *reinterpret_cast<const s16x8*>(&Vp[gr * HD + colk + p * 8]);
        #pragma unroll
        for (int e = 0; e < 8; ++e)
          Vt[(colk + p * 8 + e) * 72 + rowk] = vv[e];
      }
    }
    __syncthreads();

    // scores = Q K^T * 0.125
    f32x4 sc[4];
    #pragma unroll
    for (int f = 0; f < 4; ++f) {
      sc[f] = f32x4{0.f, 0.f, 0.f, 0.f};
      #pragma unroll
      for (int kk = 0; kk < 2; ++kk) {
        s16x8 kf = *reinterpret_cast<const s16x8*>(&Ks[(f * 16 + lr) * 72 + kk * 32 + lg * 8]);
        sc[f] = __builtin_amdgcn_mfma_f32_16x16x32_bf16(qf[kk], kf, sc[f], 0, 0, 0);
      }
    }
    #pragma unroll
    for (int f = 0; f < 4; ++f) {
      int tg = t0 + f * 16 + lr;
      bool valid = tg < SEQ;
      #pragma unroll
      for (int r = 0; r < 4; ++r)
        sc[f][r] = valid ? sc[f][r] * 0.125f : -1e30f;
    }

    // online softmax (rows = lg*4+r, stats shared across the 16 lanes of a group)
    #pragma unroll
    for (int r = 0; r < 4; ++r) {
      float mx = fmaxf(fmaxf(sc[0][r], sc[1][r]), fmaxf(sc[2][r], sc[3][r]));
      #pragma unroll
      for (int d = 1; d < 16; d <<= 1) mx = fmaxf(mx, __shfl_xor(mx, d));
      float mn = fmaxf(mrow[r], mx);
      float alpha = __expf(mrow[r] - mn);
      mrow[r] = mn;
      lsum[r] *= alpha;
      #pragma unroll
      for (int f = 0; f < 4; ++f) acco[f][r] *= alpha;
      float ps = 0.f;
      #pragma unroll
      for (int f = 0; f < 4; ++f) {
        float p = __expf(sc[f][r] - mn);
        sc[f][r] = p;
        ps += p;
      }
      #pragma unroll
      for (int d = 1; d < 16; d <<= 1) ps += __shfl_xor(ps, d);
      lsum[r] += ps;
    }

    // P -> per-wave LDS (bf16), re-fragment as MFMA A operand
    #pragma unroll
    for (int f = 0; f < 4; ++f)
      #pragma unroll
      for (int r = 0; r < 4; ++r)
        Pl[w][(lg * 4 + r) * 72 + f * 16 + lr] = (short)f2bf(sc[f][r]);

    s16x8 pf[2];
    #pragma unroll
    for (int kk = 0; kk < 2; ++kk)
      pf[kk] = *reinterpret_cast<const s16x8*>(&Pl[w][lr * 72 + kk * 32 + lg * 8]);
    #pragma unroll
    for (int f = 0; f < 4; ++f)
      #pragma unroll
      for (int kk = 0; kk < 2; ++kk) {
        s16x8 vf = *reinterpret_cast<const s16x8*>(&Vt[(f * 16 + lr) * 72 + kk * 32 + lg * 8]);
        acco[f] = __builtin_amdgcn_mfma_f32_16x16x32_bf16(pf[kk], vf, acco[f], 0, 0, 0);
      }
  }

  // normalize + write concat output (bf16)
  #pragma unroll
  for (int r = 0; r < 4; ++r) {
    int s = q0 + w * 16 + lg * 4 + r;
    if (s < SEQ) {
      float inv = 1.0f / lsum[r];
      #pragma unroll
      for (int f = 0; f < 4; ++f) {
        int d = f * 16 + lr;
        cat[((size_t)b * SEQ + s) * EMB + h * HD + d] = (short)f2bf(acco[f][r] * inv);
      }
    }
  }
}

extern "C" void kernel_launch(void* const* d_in, const int* in_sizes, int n_in,
                              void* d_out, int out_size, void* d_ws, size_t ws_size,
                              hipStream_t stream) {
  const float* x  = (const float*)d_in[0];
  const float* wq = (const float*)d_in[1];
  const float* wk = (const float*)d_in[2];
  const float* wv = (const float*)d_in[3];
  const float* wp = (const float*)d_in[4];
  const float* bp = (const float*)d_in[5];
  float* out = (float*)d_out;

  char* ws = (char*)d_ws;
  short* xb   = (short*)ws;                                   // 28,360,704 B (reused as cat)
  short* wqkv = (short*)(ws + 28360704);                      //  3,538,944 B
  short* wpb  = (short*)(ws + 28360704 + 3538944);            //  1,179,648 B
  short* qkvb = (short*)(ws + 28360704 + 3538944 + 1179648);  // 85,082,112 B
  short* cat  = xb;                                           // x dead after QKV GEMM

  cvt_x<<<6924, 256, 0, stream>>>(x, xb, 1772544);
  cvt_w<<<1152, 256, 0, stream>>>(wq, wk, wv, wp, wqkv, wpb);
  gemm_bt<0><<<145 * 18, 256, 0, stream>>>(xb, wqkv, qkvb, nullptr, nullptr, TOK, 18);
  attn<<<3840, 256, 0, stream>>>(qkvb, cat);
  gemm_bt<1><<<145 * 6, 256, 0, stream>>>(cat, wpb, nullptr, out, bp, TOK, 6);
}